// Round 18
// baseline (571.686 us; speedup 1.0000x reference)
//
#include <hip/hip_runtime.h>
#include <hip/hip_bf16.h>
#include <cstdint>
#include <cstddef>

#define L      2048
#define IN_DIM 256
#define HID    13
#define G      52            // 4*HID
#define VOCAB  50257
#define PRED_N ((size_t)L * VOCAB)
#define L2E    1.4426950408889634f
#define INV2L2E 0.34657359027997264f
#define NTX    99            // x-tiles of 512 cols (99*512 >= 50257)
#define NTILE  (NTX * 16)    // 1584 (y: 16 x 128 rows)
#define GB     254

typedef float v4f __attribute__((ext_vector_type(4)));

static __device__ __forceinline__ float fexp2(float x) { return __builtin_amdgcn_exp2f(x); }
static __device__ __forceinline__ float frcp(float x) { return __builtin_amdgcn_rcpf(x); }
static __device__ __forceinline__ float sigm(float z) { return 1.f - frcp(fexp2(z * L2E) + 1.f); }
static __device__ __forceinline__ float tanh_(float z) { return 1.f - 2.f * frcp(fexp2(z * (2.f * L2E)) + 1.f); }
static __device__ __forceinline__ float bcast(float v, int l) {
    return __int_as_float(__builtin_amdgcn_readlane(__float_as_int(v), l));
}

// u layout (both layers): u4[dir][t/4][lane64][t%4] fp32, bias folded, pre-scaled.
#define UIDX(dirv, t, l4) ((size_t)(dirv) * L * 64 + ((t) >> 2) * 256 + (l4) * 4 + ((t) & 3))

// ---------------------------------------------------------------------------
// Kernel 1: embedding gather (-> d_out embs section) + u0 = msc*(Wih0@emb+b0)
// + dec row t (zero-state decoder cell, t>=1). grid = L blocks, 160 threads.
// ---------------------------------------------------------------------------
__global__ void __launch_bounds__(160) k_emb_u0(
    const int* __restrict__ x, const float* __restrict__ embW,
    const float* __restrict__ Wih0, const float* __restrict__ b0,
    const float* __restrict__ dWih, const float* __restrict__ db,
    float* __restrict__ out_embs, float* __restrict__ u0, float* __restrict__ dec)
{
    __shared__ float se[IN_DIM];
    int t = blockIdx.x;
    int tid = threadIdx.x;            // 160
    if (tid < 128) {
        int rowx = x[t];
        float2 e = ((const float2*)(embW + (size_t)rowx * IN_DIM))[tid];
        se[2 * tid]     = e.x;
        se[2 * tid + 1] = e.y;
        ((float2*)(out_embs + (size_t)t * IN_DIM))[tid] = e;
    }
    __syncthreads();
    if (tid < 2 * G) {
        int dirg = tid / G, g = tid % G;
        int gate = g / HID, row = g % HID;
        float msc = (gate == 2) ? 2.f * L2E : L2E;
        float acc = b0[dirg * G + g];
        const float* w = Wih0 + (size_t)(dirg * G + g) * IN_DIM;
        #pragma unroll 8
        for (int k = 0; k < IN_DIM; ++k)
            acc = fmaf(w[k], se[k], acc);
        u0[UIDX(dirg, t, gate * 16 + row)] = msc * acc;
    } else if (tid < 128) {
        int p = tid - 2 * G;          // 0..23 -> zero the 2*12 pad slots
        int dirp = p / 12, pp = p % 12;
        int g4 = (pp / 3) * 16 + HID + pp % 3;
        u0[UIDX(dirp, t, g4)] = 0.f;
    } else if (tid < 128 + 2 * HID && t >= 1) {
        int j = tid - 128;            // 0..25
        int dir = j / HID, jj = j % HID;
        float v = (float)x[t - 1];
        int base = dir * G;
        float zi = fmaf(dWih[base + jj],           v, db[base + jj]);
        float zg = fmaf(dWih[base + 2 * HID + jj], v, db[base + 2 * HID + jj]);
        float zo = fmaf(dWih[base + 3 * HID + jj], v, db[base + 3 * HID + jj]);
        float c2 = sigm(zi) * tanh_(zg);
        dec[(size_t)t * (2 * HID) + j] = sigm(zo) * tanh_(c2);
    }
}

// ---------------------------------------------------------------------------
// 8 LSTM steps. M16/M32 = wave-uniform swap-placement (template). Only group 0
// (lanes 0-12) carries live h/c. s_nop 1 before each permlane swap REQUIRED
// (gfx950 VALU->permlane wait state, r13). 7-acc matvec (depth 6 to z) and
// h = fma(-2so, r, so) (r17) minimize dependent levels (17 total).
// ---------------------------------------------------------------------------
template<bool DOUT, int DIR, bool M16, bool M32>
static __device__ __forceinline__ void compute8(
    v4f af, v4f bf, const float* whh, float kcv, float onev,
    float& h, float& c, float* outp, int pstep)
{
    #pragma unroll
    for (int k = 0; k < 8; ++k) {
        float uk;
        if (DIR == 0) uk = (k < 4) ? af[k] : bf[k - 4];
        else          uk = (k < 4) ? bf[3 - k] : af[7 - k];
        float h0 = bcast(h, 0), h1 = bcast(h, 1), h2 = bcast(h, 2), h3 = bcast(h, 3);
        float h4 = bcast(h, 4), h5 = bcast(h, 5), h6 = bcast(h, 6), h7 = bcast(h, 7);
        float h8_ = bcast(h, 8), h9 = bcast(h, 9), h10 = bcast(h, 10), h11 = bcast(h, 11);
        float h12 = bcast(h, 12);
        float a0 = fmaf(whh[0], h0, uk);   a0 = fmaf(whh[1], h1, a0);
        float a1 = whh[2] * h2;            a1 = fmaf(whh[3], h3, a1);
        float a2 = whh[4] * h4;            a2 = fmaf(whh[5], h5, a2);
        float a3 = whh[6] * h6;            a3 = fmaf(whh[7], h7, a3);
        float a4 = whh[8] * h8_;           a4 = fmaf(whh[9], h9, a4);
        float a5 = whh[10] * h10;          a5 = fmaf(whh[11], h11, a5);
        float a6 = whh[12] * h12;
        float z = ((a0 + a1) + (a2 + a3)) + ((a4 + a5) + a6);
        float act = fmaf(-kcv, frcp(fexp2(z) + 1.f), onev);
        float pa = act, pb = act;
        asm("s_nop 1\n\tv_permlane16_swap_b32 %0, %1" : "+v"(pa), "+v"(pb));
        float sf = M16 ? pa : pb;                 // act[lane^16] (valid lanes 0-15)
        float qa = act, qb = act;
        asm("s_nop 1\n\tv_permlane32_swap_b32 %0, %1" : "+v"(qa), "+v"(qb));
        float tg = M32 ? qa : qb;                 // act[lane^32] (valid lanes 0-31)
        float ra = tg, rb = tg;
        asm("s_nop 1\n\tv_permlane16_swap_b32 %0, %1" : "+v"(ra), "+v"(rb));
        float so = M16 ? ra : rb;                 // act[lane^48] (valid lanes 0-15)
        float so2 = so + so;                      // off critical path
        float c2 = fmaf(sf, c, act * tg);         // 2*L2E units (grp0 valid)
        float r = frcp(fexp2(c2) + 1.f);
        h = fmaf(-so2, r, so);                    // = so * tanh(c2-units)
        c = c2;
        if (DOUT) outp[k * pstep] = h;
    }
}

// ---------------------------------------------------------------------------
// Chain loop: float4 u loads (2 per 8 steps), ping-pong prefetch.
// ---------------------------------------------------------------------------
template<bool DOUT, int DIR, bool M16, bool M32>
static __device__ __forceinline__ void chain_core(
    const float* ubase, const float* whh, float kcv, float onev,
    float* outp, int pstep_out, float& hout, float& cout)
{
    // quad-a float offset for 8-step chunk starting at step s
    #define QOFF(s) ((DIR == 0) ? (s) * 64 : (L - 8 - (s)) * 64)
    v4f a0 = *(const v4f*)(ubase + QOFF(0));
    v4f b0 = *(const v4f*)(ubase + QOFF(0) + 256);
    v4f a1 = *(const v4f*)(ubase + QOFF(8));
    v4f b1 = *(const v4f*)(ubase + QOFF(8) + 256);
    float h = 0.f, c = 0.f;
    for (int tcb = 0; tcb < L; tcb += 16) {
        compute8<DOUT, DIR, M16, M32>(a0, b0, whh, kcv, onev, h, c, outp, pstep_out);
        if (DOUT) outp += 8 * pstep_out;
        if (tcb + 16 < L) {
            a0 = *(const v4f*)(ubase + QOFF(tcb + 16));
            b0 = *(const v4f*)(ubase + QOFF(tcb + 16) + 256);
        }
        compute8<DOUT, DIR, M16, M32>(a1, b1, whh, kcv, onev, h, c, outp, pstep_out);
        if (DOUT) outp += 8 * pstep_out;
        if (tcb + 24 < L) {
            a1 = *(const v4f*)(ubase + QOFF(tcb + 24));
            b1 = *(const v4f*)(ubase + QOFF(tcb + 24) + 256);
        }
    }
    #undef QOFF
    hout = h; cout = c;
}

template<bool DOUT>
static __device__ __forceinline__ void run_chain(
    const float* u, const float* Whh, float* out0p,
    float* finh, float* finc, int chain_base, int dir, int lane)
{
    int lg16 = lane & 15, gate = lane >> 4;
    int rsrc = gate * HID + (lg16 < HID ? lg16 : HID - 1);   // clamp pad rows
    float kcv, onev;
    if (gate == 2)      { kcv = 2.f;        onev = 1.f; }         // g: tanh
    else if (gate == 0) { kcv = 2.f * L2E;  onev = 2.f * L2E; }   // i: prescaled sigmoid
    else                { kcv = 1.f;        onev = 1.f; }         // f,o: sigmoid
    float msc = (gate == 2) ? 2.f * L2E : L2E;
    float whh[HID];
    #pragma unroll
    for (int k = 0; k < HID; ++k) whh[k] = msc * Whh[(dir * G + rsrc) * HID + k];

    // swap placement detection; lane-0 value valid for group 0 -> uniform dispatch
    int ia = lane, ib = lane;
    asm("s_nop 1\n\tv_permlane16_swap_b32 %0, %1" : "+v"(ia), "+v"(ib));
    int m16i = __builtin_amdgcn_readlane((ia == (lane ^ 16)) ? 1 : 0, 0);
    int ja = lane, jb = lane;
    asm("s_nop 1\n\tv_permlane32_swap_b32 %0, %1" : "+v"(ja), "+v"(jb));
    int m32i = __builtin_amdgcn_readlane((ja == (lane ^ 32)) ? 1 : 0, 0);

    const float* ubase = u + (size_t)dir * L * 64 + lane * 4;
    int pstep_out = dir ? -64 : 64;
    float* outp = out0p ? out0p + ((size_t)dir * L + (dir ? L - 1 : 0)) * 64 + lane : (float*)nullptr;

    float h, c;
    if (dir == 0) {
        if (m16i) { if (m32i) chain_core<DOUT,0,true, true >(ubase, whh, kcv, onev, outp, pstep_out, h, c);
                    else      chain_core<DOUT,0,true, false>(ubase, whh, kcv, onev, outp, pstep_out, h, c); }
        else      { if (m32i) chain_core<DOUT,0,false,true >(ubase, whh, kcv, onev, outp, pstep_out, h, c);
                    else      chain_core<DOUT,0,false,false>(ubase, whh, kcv, onev, outp, pstep_out, h, c); }
    } else {
        if (m16i) { if (m32i) chain_core<DOUT,1,true, true >(ubase, whh, kcv, onev, outp, pstep_out, h, c);
                    else      chain_core<DOUT,1,true, false>(ubase, whh, kcv, onev, outp, pstep_out, h, c); }
        else      { if (m32i) chain_core<DOUT,1,false,true >(ubase, whh, kcv, onev, outp, pstep_out, h, c);
                    else      chain_core<DOUT,1,false,false>(ubase, whh, kcv, onev, outp, pstep_out, h, c); }
    }

    if (lane < HID) {
        finh[(chain_base + dir) * HID + lane] = h;
        finc[(chain_base + dir) * HID + lane] = c * INV2L2E;
    }
}

// ---------------------------------------------------------------------------
// Phase 0: grid=(2+GB) x 256. Blocks 0,1 = layer-0 chains (wave 0 only).
// Blocks >=2 = GEMM workers: 512-col x 128-row tiles.
// ---------------------------------------------------------------------------
__global__ void __launch_bounds__(256) k_phase0(
    const float* __restrict__ u, const float* __restrict__ Whh,
    float* __restrict__ out0p, float* __restrict__ finh, float* __restrict__ finc,
    const float* __restrict__ dec, const float* __restrict__ outW,
    const float* __restrict__ outb, float* __restrict__ preds)
{
    __shared__ float sd[128][28];
    int bid = blockIdx.x;
    int tid = threadIdx.x;
    if (bid < 2) {
        if (tid >= 64) return;
        __builtin_amdgcn_s_setprio(3);
        run_chain<true>(u, Whh, out0p, finh, finc, 0, bid, tid);
        return;
    }
    // ---- GEMM worker ----
    __builtin_amdgcn_s_setprio(0);
    int b = bid - 2;                           // 0..GB-1
    const int q = NTILE / GB, r = NTILE % GB;  // 6, 60
    int start = b * q + (b < r ? b : r);
    int cnt   = q + (b < r ? 1 : 0);
    for (int tt = 0; tt < cnt; ++tt) {
        int tile = start + tt;
        int ix = tile % NTX, iy = tile / NTX;
        int nbase = ix * 512, i0 = iy * 128;
        __syncthreads();
        for (int li = tid; li < 128 * 26; li += 256) {
            int rr = li / 26, cc = li % 26;
            sd[rr][cc] = dec[(size_t)(i0 + rr) * 26 + cc];
        }
        __syncthreads();
        int n0 = nbase + tid, n1 = nbase + 256 + tid;
        bool a0 = n0 < VOCAB, a1 = n1 < VOCAB;
        float w0[26], w1[26], b0v = 0.f, b1v = 0.f;
        #pragma unroll
        for (int k = 0; k < 26; ++k) { w0[k] = 0.f; w1[k] = 0.f; }
        if (a0) { const float* w = outW + (size_t)n0 * 26;
            #pragma unroll
            for (int k = 0; k < 26; ++k) w0[k] = w[k];
            b0v = outb[n0]; }
        if (a1) { const float* w = outW + (size_t)n1 * 26;
            #pragma unroll
            for (int k = 0; k < 26; ++k) w1[k] = w[k];
            b1v = outb[n1]; }
        for (int i = 0; i < 128; ++i) {
            int grow = i0 + i;
            float acc0 = b0v, acc1 = b1v;
            const float* dr = sd[i];
            #pragma unroll
            for (int k = 0; k < 26; ++k) {
                float d = dr[k];
                acc0 = fmaf(d, w0[k], acc0);
                acc1 = fmaf(d, w1[k], acc1);
            }
            if (grow != 0) {                   // row 0 written by k_tail
                size_t rb = (size_t)grow * VOCAB;
                if (a0) preds[rb + n0] = acc0;
                if (a1) preds[rb + n1] = acc1;
            }
        }
    }
}

// ---------------------------------------------------------------------------
// Kernel 4: u1 = msc*(Wih1 @ out0 + b1). out0p is [dir][t][64]; u1 in u4 layout.
// ---------------------------------------------------------------------------
__global__ void k_u1(const float* __restrict__ out0p, const float* __restrict__ Wih1,
                     const float* __restrict__ b1, float* __restrict__ u1)
{
    int idx = blockIdx.x * blockDim.x + threadIdx.x;
    if (idx >= L * 2 * 64) return;
    int t    = idx >> 7;
    int remv = idx & 127;
    int d1   = remv >> 6;
    int lane = remv & 63;
    int gate = lane >> 4, row = lane & 15;
    size_t oidx = UIDX(d1, t, lane);
    if (row >= HID) { u1[oidx] = 0.f; return; }
    int g = gate * HID + row;
    float msc = (gate == 2) ? 2.f * L2E : L2E;
    float acc = b1[d1 * G + g];
    const float* w = Wih1 + (size_t)(d1 * G + g) * (2 * HID);
    const float* o0 = out0p + (size_t)t * 64;            // dir0 h at lanes 0..12
    const float* o1 = out0p + ((size_t)L + t) * 64;      // dir1 h at lanes 0..12
    #pragma unroll
    for (int k = 0; k < HID; ++k)
        acc = fmaf(w[k], o0[k], acc);
    #pragma unroll
    for (int k = 0; k < HID; ++k)
        acc = fmaf(w[HID + k], o1[k], acc);
    u1[oidx] = msc * acc;
}

// ---------------------------------------------------------------------------
// Phase 1: chain-only, 2 blocks x 64 (clean chain)
// ---------------------------------------------------------------------------
__global__ void __launch_bounds__(64) k_phase1(
    const float* __restrict__ u, const float* __restrict__ Whh,
    float* __restrict__ finh, float* __restrict__ finc)
{
    run_chain<false>(u, Whh, (float*)nullptr, finh, finc, 2, blockIdx.x, threadIdx.x);
}

// ---------------------------------------------------------------------------
// Kernel k_tail: projections + decoder step 0 + preds row 0, fused.
// grid = ceil(VOCAB/256) blocks x 256 thr; each block redundantly computes
// the (tiny) final-state work in LDS, then its 256-wide slice of row 0.
// ---------------------------------------------------------------------------
__global__ void __launch_bounds__(256) k_tail(
    const float* __restrict__ fin_h, const float* __restrict__ fin_c,
    const float* __restrict__ p1W, const float* __restrict__ p1b,
    const float* __restrict__ p2W, const float* __restrict__ p2b,
    const float* __restrict__ dWih, const float* __restrict__ dWhh,
    const float* __restrict__ db,
    const float* __restrict__ outW, const float* __restrict__ outb,
    float* __restrict__ preds)
{
    __shared__ float sh[2 * HID], sc[2 * HID], sz[2][G], d0[2 * HID];
    int tid = threadIdx.x;
    if (tid < 4 * HID) {
        int r = tid < 2 * HID ? tid : tid - 2 * HID;
        const float* W   = tid < 2 * HID ? p1W : p2W;
        const float* src = tid < 2 * HID ? fin_h : fin_c;
        float acc = tid < 2 * HID ? p1b[r] : p2b[r];
        for (int k = 0; k < 4 * HID; ++k) acc = fmaf(W[r * 4 * HID + k], src[k], acc);
        if (tid < 2 * HID) sh[r] = acc; else sc[r] = acc;
    }
    __syncthreads();
    if (tid < 2 * G) {
        int dir = tid / G, g = tid % G;
        float acc = db[dir * G + g] - dWih[dir * G + g];   // input = -1.0
        for (int k = 0; k < HID; ++k)
            acc = fmaf(dWhh[(dir * G + g) * HID + k], sh[dir * HID + k], acc);
        sz[dir][g] = acc;
    }
    __syncthreads();
    if (tid < 2 * HID) {
        int dir = tid / HID, j = tid % HID;
        float si = sigm(sz[dir][j]);
        float sf = sigm(sz[dir][HID + j]);
        float tg = tanh_(sz[dir][2 * HID + j]);
        float so = sigm(sz[dir][3 * HID + j]);
        float c2 = fmaf(sf, sc[dir * HID + j], si * tg);
        d0[dir * HID + j] = so * tanh_(c2);
    }
    __syncthreads();
    int n = blockIdx.x * 256 + tid;
    if (n < VOCAB) {
        float acc = outb[n];
        const float* w = outW + (size_t)n * 26;
        #pragma unroll
        for (int k = 0; k < 26; ++k) acc = fmaf(w[k], d0[k], acc);
        preds[n] = acc;
    }
}

// ---------------------------------------------------------------------------
extern "C" void kernel_launch(void* const* d_in, const int* in_sizes, int n_in,
                              void* d_out, int out_size, void* d_ws, size_t ws_size,
                              hipStream_t stream)
{
    (void)in_sizes; (void)n_in; (void)out_size; (void)ws_size;

    const int*   x     = (const int*)d_in[0];
    const float* embW  = (const float*)d_in[1];
    const float* eWih0 = (const float*)d_in[2];
    const float* eWhh0 = (const float*)d_in[3];
    const float* eb0   = (const float*)d_in[4];
    const float* eWih1 = (const float*)d_in[5];
    const float* eWhh1 = (const float*)d_in[6];
    const float* eb1   = (const float*)d_in[7];
    const float* p1W   = (const float*)d_in[8];
    const float* p1b   = (const float*)d_in[9];
    const float* p2W   = (const float*)d_in[10];
    const float* p2b   = (const float*)d_in[11];
    const float* dWih  = (const float*)d_in[12];
    const float* dWhh  = (const float*)d_in[13];
    const float* db    = (const float*)d_in[14];
    const float* outW  = (const float*)d_in[15];
    const float* outb  = (const float*)d_in[16];

    float* ws    = (float*)d_ws;
    float* u0    = ws;                       // 2*L*64
    float* u1    = u0 + 2 * L * 64;          // 2*L*64
    float* out0p = u1 + 2 * L * 64;          // 2*L*64
    float* dec   = out0p + 2 * L * 64;       // L*26
    float* fin_h = dec + L * 2 * HID;        // 64
    float* fin_c = fin_h + 64;               // 64

    float* preds    = (float*)d_out;
    float* out_embs = preds + PRED_N;

    hipLaunchKernelGGL(k_emb_u0, dim3(L), dim3(160), 0, stream,
                       x, embW, eWih0, eb0, dWih, db, out_embs, u0, dec);

    hipLaunchKernelGGL(k_phase0, dim3(2 + GB), dim3(256), 0, stream,
                       u0, eWhh0, out0p, fin_h, fin_c,
                       dec, outW, outb, preds);

    hipLaunchKernelGGL(k_u1, dim3((L * 2 * 64 + 255) / 256), dim3(256), 0, stream,
                       out0p, eWih1, eb1, u1);

    hipLaunchKernelGGL(k_phase1, dim3(2), dim3(64), 0, stream,
                       u1, eWhh1, fin_h, fin_c);

    hipLaunchKernelGGL(k_tail, dim3((VOCAB + 255) / 256), dim3(256), 0, stream,
                       fin_h, fin_c, p1W, p1b, p2W, p2b, dWih, dWhh, db,
                       outW, outb, preds);
}

// Round 19
// 558.814 us; speedup vs baseline: 1.0230x; 1.0230x over previous
//
#include <hip/hip_runtime.h>
#include <hip/hip_bf16.h>
#include <cstdint>
#include <cstddef>

#define L      2048
#define IN_DIM 256
#define HID    13
#define G      52            // 4*HID
#define VOCAB  50257
#define PRED_N ((size_t)L * VOCAB)
#define L2E    1.4426950408889634f
#define INV2L2E 0.34657359027997264f
#define NTX    99            // x-tiles of 512 cols (99*512 >= 50257)
#define NTILE  (NTX * 16)    // 1584 (y: 16 x 128 rows)
#define GB     254

typedef float v4f __attribute__((ext_vector_type(4)));

static __device__ __forceinline__ float fexp2(float x) { return __builtin_amdgcn_exp2f(x); }
static __device__ __forceinline__ float frcp(float x) { return __builtin_amdgcn_rcpf(x); }
static __device__ __forceinline__ float sigm(float z) { return 1.f - frcp(fexp2(z * L2E) + 1.f); }
static __device__ __forceinline__ float tanh_(float z) { return 1.f - 2.f * frcp(fexp2(z * (2.f * L2E)) + 1.f); }
static __device__ __forceinline__ float bcast(float v, int l) {
    return __int_as_float(__builtin_amdgcn_readlane(__float_as_int(v), l));
}

// u layout (both layers): u4[dir][t/4][lane64][t%4] fp32, bias folded, pre-scaled.
#define UIDX(dirv, t, l4) ((size_t)(dirv) * L * 64 + ((t) >> 2) * 256 + (l4) * 4 + ((t) & 3))

// ---------------------------------------------------------------------------
// Kernel 1: embedding gather (-> d_out embs section) + u0 = msc*(Wih0@emb+b0)
// + dec row t (zero-state decoder cell, t>=1). grid = L blocks, 160 threads.
// ---------------------------------------------------------------------------
__global__ void __launch_bounds__(160) k_emb_u0(
    const int* __restrict__ x, const float* __restrict__ embW,
    const float* __restrict__ Wih0, const float* __restrict__ b0,
    const float* __restrict__ dWih, const float* __restrict__ db,
    float* __restrict__ out_embs, float* __restrict__ u0, float* __restrict__ dec)
{
    __shared__ float se[IN_DIM];
    int t = blockIdx.x;
    int tid = threadIdx.x;            // 160
    if (tid < 128) {
        int rowx = x[t];
        float2 e = ((const float2*)(embW + (size_t)rowx * IN_DIM))[tid];
        se[2 * tid]     = e.x;
        se[2 * tid + 1] = e.y;
        ((float2*)(out_embs + (size_t)t * IN_DIM))[tid] = e;
    }
    __syncthreads();
    if (tid < 2 * G) {
        int dirg = tid / G, g = tid % G;
        int gate = g / HID, row = g % HID;
        float msc = (gate == 2) ? 2.f * L2E : L2E;
        float acc = b0[dirg * G + g];
        const float* w = Wih0 + (size_t)(dirg * G + g) * IN_DIM;
        #pragma unroll 8
        for (int k = 0; k < IN_DIM; ++k)
            acc = fmaf(w[k], se[k], acc);
        u0[UIDX(dirg, t, gate * 16 + row)] = msc * acc;
    } else if (tid < 128) {
        int p = tid - 2 * G;          // 0..23 -> zero the 2*12 pad slots
        int dirp = p / 12, pp = p % 12;
        int g4 = (pp / 3) * 16 + HID + pp % 3;
        u0[UIDX(dirp, t, g4)] = 0.f;
    } else if (tid < 128 + 2 * HID && t >= 1) {
        int j = tid - 128;            // 0..25
        int dir = j / HID, jj = j % HID;
        float v = (float)x[t - 1];
        int base = dir * G;
        float zi = fmaf(dWih[base + jj],           v, db[base + jj]);
        float zg = fmaf(dWih[base + 2 * HID + jj], v, db[base + 2 * HID + jj]);
        float zo = fmaf(dWih[base + 3 * HID + jj], v, db[base + 3 * HID + jj]);
        float c2 = sigm(zi) * tanh_(zg);
        dec[(size_t)t * (2 * HID) + j] = sigm(zo) * tanh_(c2);
    }
}

// ---------------------------------------------------------------------------
// 8 LSTM steps. M16/M32 = wave-uniform swap-placement (template). Only group 0
// (lanes 0-12) carries live h/c. s_nop 1 before each permlane swap REQUIRED
// (gfx950 VALU->permlane wait state, r13). 4-acc matvec tree (r9/r17-proven)
// + h = fma(-2so, r, so) final-level fusion (r17). 18 dependent levels.
// ---------------------------------------------------------------------------
template<bool DOUT, int DIR, bool M16, bool M32>
static __device__ __forceinline__ void compute8(
    v4f af, v4f bf, const float* whh, float kcv, float onev,
    float& h, float& c, float* outp, int pstep)
{
    #pragma unroll
    for (int k = 0; k < 8; ++k) {
        float uk;
        if (DIR == 0) uk = (k < 4) ? af[k] : bf[k - 4];
        else          uk = (k < 4) ? bf[3 - k] : af[7 - k];
        float h0 = bcast(h, 0), h1 = bcast(h, 1), h2 = bcast(h, 2), h3 = bcast(h, 3);
        float h4 = bcast(h, 4), h5 = bcast(h, 5), h6 = bcast(h, 6), h7 = bcast(h, 7);
        float h8_ = bcast(h, 8), h9 = bcast(h, 9), h10 = bcast(h, 10), h11 = bcast(h, 11);
        float h12 = bcast(h, 12);
        float A = fmaf(whh[0], h0, uk);
        float B = whh[1] * h1;
        float C = whh[2] * h2;
        float D = whh[3] * h3;
        A = fmaf(whh[4], h4, A);   B = fmaf(whh[5], h5, B);
        C = fmaf(whh[6], h6, C);   D = fmaf(whh[7], h7, D);
        A = fmaf(whh[8], h8_, A);  B = fmaf(whh[9], h9, B);
        C = fmaf(whh[10], h10, C); D = fmaf(whh[11], h11, D);
        A = fmaf(whh[12], h12, A);
        float z = (A + B) + (C + D);
        float act = fmaf(-kcv, frcp(fexp2(z) + 1.f), onev);
        float pa = act, pb = act;
        asm("s_nop 1\n\tv_permlane16_swap_b32 %0, %1" : "+v"(pa), "+v"(pb));
        float sf = M16 ? pa : pb;                 // act[lane^16] (valid lanes 0-15)
        float qa = act, qb = act;
        asm("s_nop 1\n\tv_permlane32_swap_b32 %0, %1" : "+v"(qa), "+v"(qb));
        float tg = M32 ? qa : qb;                 // act[lane^32] (valid lanes 0-31)
        float ra = tg, rb = tg;
        asm("s_nop 1\n\tv_permlane16_swap_b32 %0, %1" : "+v"(ra), "+v"(rb));
        float so = M16 ? ra : rb;                 // act[lane^48] (valid lanes 0-15)
        float so2 = so + so;                      // off critical path
        float c2 = fmaf(sf, c, act * tg);         // 2*L2E units (grp0 valid)
        float r = frcp(fexp2(c2) + 1.f);
        h = fmaf(-so2, r, so);                    // = so * tanh(c2-units)
        c = c2;
        if (DOUT) outp[k * pstep] = h;
    }
}

// ---------------------------------------------------------------------------
// Chain loop: float4 u loads (2 per 8 steps), ping-pong prefetch.
// ---------------------------------------------------------------------------
template<bool DOUT, int DIR, bool M16, bool M32>
static __device__ __forceinline__ void chain_core(
    const float* ubase, const float* whh, float kcv, float onev,
    float* outp, int pstep_out, float& hout, float& cout)
{
    // quad-a float offset for 8-step chunk starting at step s
    #define QOFF(s) ((DIR == 0) ? (s) * 64 : (L - 8 - (s)) * 64)
    v4f a0 = *(const v4f*)(ubase + QOFF(0));
    v4f b0 = *(const v4f*)(ubase + QOFF(0) + 256);
    v4f a1 = *(const v4f*)(ubase + QOFF(8));
    v4f b1 = *(const v4f*)(ubase + QOFF(8) + 256);
    float h = 0.f, c = 0.f;
    for (int tcb = 0; tcb < L; tcb += 16) {
        compute8<DOUT, DIR, M16, M32>(a0, b0, whh, kcv, onev, h, c, outp, pstep_out);
        if (DOUT) outp += 8 * pstep_out;
        if (tcb + 16 < L) {
            a0 = *(const v4f*)(ubase + QOFF(tcb + 16));
            b0 = *(const v4f*)(ubase + QOFF(tcb + 16) + 256);
        }
        compute8<DOUT, DIR, M16, M32>(a1, b1, whh, kcv, onev, h, c, outp, pstep_out);
        if (DOUT) outp += 8 * pstep_out;
        if (tcb + 24 < L) {
            a1 = *(const v4f*)(ubase + QOFF(tcb + 24));
            b1 = *(const v4f*)(ubase + QOFF(tcb + 24) + 256);
        }
    }
    #undef QOFF
    hout = h; cout = c;
}

template<bool DOUT>
static __device__ __forceinline__ void run_chain(
    const float* u, const float* Whh, float* out0p,
    float* finh, float* finc, int chain_base, int dir, int lane)
{
    int lg16 = lane & 15, gate = lane >> 4;
    int rsrc = gate * HID + (lg16 < HID ? lg16 : HID - 1);   // clamp pad rows
    float kcv, onev;
    if (gate == 2)      { kcv = 2.f;        onev = 1.f; }         // g: tanh
    else if (gate == 0) { kcv = 2.f * L2E;  onev = 2.f * L2E; }   // i: prescaled sigmoid
    else                { kcv = 1.f;        onev = 1.f; }         // f,o: sigmoid
    float msc = (gate == 2) ? 2.f * L2E : L2E;
    float whh[HID];
    #pragma unroll
    for (int k = 0; k < HID; ++k) whh[k] = msc * Whh[(dir * G + rsrc) * HID + k];

    // swap placement detection; lane-0 value valid for group 0 -> uniform dispatch
    int ia = lane, ib = lane;
    asm("s_nop 1\n\tv_permlane16_swap_b32 %0, %1" : "+v"(ia), "+v"(ib));
    int m16i = __builtin_amdgcn_readlane((ia == (lane ^ 16)) ? 1 : 0, 0);
    int ja = lane, jb = lane;
    asm("s_nop 1\n\tv_permlane32_swap_b32 %0, %1" : "+v"(ja), "+v"(jb));
    int m32i = __builtin_amdgcn_readlane((ja == (lane ^ 32)) ? 1 : 0, 0);

    const float* ubase = u + (size_t)dir * L * 64 + lane * 4;
    int pstep_out = dir ? -64 : 64;
    float* outp = out0p ? out0p + ((size_t)dir * L + (dir ? L - 1 : 0)) * 64 + lane : (float*)nullptr;

    float h, c;
    if (dir == 0) {
        if (m16i) { if (m32i) chain_core<DOUT,0,true, true >(ubase, whh, kcv, onev, outp, pstep_out, h, c);
                    else      chain_core<DOUT,0,true, false>(ubase, whh, kcv, onev, outp, pstep_out, h, c); }
        else      { if (m32i) chain_core<DOUT,0,false,true >(ubase, whh, kcv, onev, outp, pstep_out, h, c);
                    else      chain_core<DOUT,0,false,false>(ubase, whh, kcv, onev, outp, pstep_out, h, c); }
    } else {
        if (m16i) { if (m32i) chain_core<DOUT,1,true, true >(ubase, whh, kcv, onev, outp, pstep_out, h, c);
                    else      chain_core<DOUT,1,true, false>(ubase, whh, kcv, onev, outp, pstep_out, h, c); }
        else      { if (m32i) chain_core<DOUT,1,false,true >(ubase, whh, kcv, onev, outp, pstep_out, h, c);
                    else      chain_core<DOUT,1,false,false>(ubase, whh, kcv, onev, outp, pstep_out, h, c); }
    }

    if (lane < HID) {
        finh[(chain_base + dir) * HID + lane] = h;
        finc[(chain_base + dir) * HID + lane] = c * INV2L2E;
    }
}

// ---------------------------------------------------------------------------
// Phase 0: grid=(2+GB) x 256. Blocks 0,1 = layer-0 chains (wave 0 only).
// Blocks >=2 = GEMM workers: 512-col x 128-row tiles.
// ---------------------------------------------------------------------------
__global__ void __launch_bounds__(256) k_phase0(
    const float* __restrict__ u, const float* __restrict__ Whh,
    float* __restrict__ out0p, float* __restrict__ finh, float* __restrict__ finc,
    const float* __restrict__ dec, const float* __restrict__ outW,
    const float* __restrict__ outb, float* __restrict__ preds)
{
    __shared__ float sd[128][28];
    int bid = blockIdx.x;
    int tid = threadIdx.x;
    if (bid < 2) {
        if (tid >= 64) return;
        __builtin_amdgcn_s_setprio(3);
        run_chain<true>(u, Whh, out0p, finh, finc, 0, bid, tid);
        return;
    }
    // ---- GEMM worker ----
    __builtin_amdgcn_s_setprio(0);
    int b = bid - 2;                           // 0..GB-1
    const int q = NTILE / GB, r = NTILE % GB;  // 6, 60
    int start = b * q + (b < r ? b : r);
    int cnt   = q + (b < r ? 1 : 0);
    for (int tt = 0; tt < cnt; ++tt) {
        int tile = start + tt;
        int ix = tile % NTX, iy = tile / NTX;
        int nbase = ix * 512, i0 = iy * 128;
        __syncthreads();
        for (int li = tid; li < 128 * 26; li += 256) {
            int rr = li / 26, cc = li % 26;
            sd[rr][cc] = dec[(size_t)(i0 + rr) * 26 + cc];
        }
        __syncthreads();
        int n0 = nbase + tid, n1 = nbase + 256 + tid;
        bool a0 = n0 < VOCAB, a1 = n1 < VOCAB;
        float w0[26], w1[26], b0v = 0.f, b1v = 0.f;
        #pragma unroll
        for (int k = 0; k < 26; ++k) { w0[k] = 0.f; w1[k] = 0.f; }
        if (a0) { const float* w = outW + (size_t)n0 * 26;
            #pragma unroll
            for (int k = 0; k < 26; ++k) w0[k] = w[k];
            b0v = outb[n0]; }
        if (a1) { const float* w = outW + (size_t)n1 * 26;
            #pragma unroll
            for (int k = 0; k < 26; ++k) w1[k] = w[k];
            b1v = outb[n1]; }
        for (int i = 0; i < 128; ++i) {
            int grow = i0 + i;
            float acc0 = b0v, acc1 = b1v;
            const float* dr = sd[i];
            #pragma unroll
            for (int k = 0; k < 26; ++k) {
                float d = dr[k];
                acc0 = fmaf(d, w0[k], acc0);
                acc1 = fmaf(d, w1[k], acc1);
            }
            if (grow != 0) {                   // row 0 written by k_tail
                size_t rb = (size_t)grow * VOCAB;
                if (a0) preds[rb + n0] = acc0;
                if (a1) preds[rb + n1] = acc1;
            }
        }
    }
}

// ---------------------------------------------------------------------------
// Kernel 4: u1 = msc*(Wih1 @ out0 + b1). out0p is [dir][t][64]; u1 in u4 layout.
// ---------------------------------------------------------------------------
__global__ void k_u1(const float* __restrict__ out0p, const float* __restrict__ Wih1,
                     const float* __restrict__ b1, float* __restrict__ u1)
{
    int idx = blockIdx.x * blockDim.x + threadIdx.x;
    if (idx >= L * 2 * 64) return;
    int t    = idx >> 7;
    int remv = idx & 127;
    int d1   = remv >> 6;
    int lane = remv & 63;
    int gate = lane >> 4, row = lane & 15;
    size_t oidx = UIDX(d1, t, lane);
    if (row >= HID) { u1[oidx] = 0.f; return; }
    int g = gate * HID + row;
    float msc = (gate == 2) ? 2.f * L2E : L2E;
    float acc = b1[d1 * G + g];
    const float* w = Wih1 + (size_t)(d1 * G + g) * (2 * HID);
    const float* o0 = out0p + (size_t)t * 64;            // dir0 h at lanes 0..12
    const float* o1 = out0p + ((size_t)L + t) * 64;      // dir1 h at lanes 0..12
    #pragma unroll
    for (int k = 0; k < HID; ++k)
        acc = fmaf(w[k], o0[k], acc);
    #pragma unroll
    for (int k = 0; k < HID; ++k)
        acc = fmaf(w[HID + k], o1[k], acc);
    u1[oidx] = msc * acc;
}

// ---------------------------------------------------------------------------
// Phase 1: chain-only, 2 blocks x 64 (clean chain)
// ---------------------------------------------------------------------------
__global__ void __launch_bounds__(64) k_phase1(
    const float* __restrict__ u, const float* __restrict__ Whh,
    float* __restrict__ finh, float* __restrict__ finc)
{
    run_chain<false>(u, Whh, (float*)nullptr, finh, finc, 2, blockIdx.x, threadIdx.x);
}

// ---------------------------------------------------------------------------
// Kernel k_tail: projections + decoder step 0 + preds row 0, fused.
// grid = ceil(VOCAB/256) blocks x 256 thr; each block redundantly computes
// the (tiny) final-state work in LDS, then its 256-wide slice of row 0.
// ---------------------------------------------------------------------------
__global__ void __launch_bounds__(256) k_tail(
    const float* __restrict__ fin_h, const float* __restrict__ fin_c,
    const float* __restrict__ p1W, const float* __restrict__ p1b,
    const float* __restrict__ p2W, const float* __restrict__ p2b,
    const float* __restrict__ dWih, const float* __restrict__ dWhh,
    const float* __restrict__ db,
    const float* __restrict__ outW, const float* __restrict__ outb,
    float* __restrict__ preds)
{
    __shared__ float sh[2 * HID], sc[2 * HID], sz[2][G], d0[2 * HID];
    int tid = threadIdx.x;
    if (tid < 4 * HID) {
        int r = tid < 2 * HID ? tid : tid - 2 * HID;
        const float* W   = tid < 2 * HID ? p1W : p2W;
        const float* src = tid < 2 * HID ? fin_h : fin_c;
        float acc = tid < 2 * HID ? p1b[r] : p2b[r];
        for (int k = 0; k < 4 * HID; ++k) acc = fmaf(W[r * 4 * HID + k], src[k], acc);
        if (tid < 2 * HID) sh[r] = acc; else sc[r] = acc;
    }
    __syncthreads();
    if (tid < 2 * G) {
        int dir = tid / G, g = tid % G;
        float acc = db[dir * G + g] - dWih[dir * G + g];   // input = -1.0
        for (int k = 0; k < HID; ++k)
            acc = fmaf(dWhh[(dir * G + g) * HID + k], sh[dir * HID + k], acc);
        sz[dir][g] = acc;
    }
    __syncthreads();
    if (tid < 2 * HID) {
        int dir = tid / HID, j = tid % HID;
        float si = sigm(sz[dir][j]);
        float sf = sigm(sz[dir][HID + j]);
        float tg = tanh_(sz[dir][2 * HID + j]);
        float so = sigm(sz[dir][3 * HID + j]);
        float c2 = fmaf(sf, sc[dir * HID + j], si * tg);
        d0[dir * HID + j] = so * tanh_(c2);
    }
    __syncthreads();
    int n = blockIdx.x * 256 + tid;
    if (n < VOCAB) {
        float acc = outb[n];
        const float* w = outW + (size_t)n * 26;
        #pragma unroll
        for (int k = 0; k < 26; ++k) acc = fmaf(w[k], d0[k], acc);
        preds[n] = acc;
    }
}

// ---------------------------------------------------------------------------
extern "C" void kernel_launch(void* const* d_in, const int* in_sizes, int n_in,
                              void* d_out, int out_size, void* d_ws, size_t ws_size,
                              hipStream_t stream)
{
    (void)in_sizes; (void)n_in; (void)out_size; (void)ws_size;

    const int*   x     = (const int*)d_in[0];
    const float* embW  = (const float*)d_in[1];
    const float* eWih0 = (const float*)d_in[2];
    const float* eWhh0 = (const float*)d_in[3];
    const float* eb0   = (const float*)d_in[4];
    const float* eWih1 = (const float*)d_in[5];
    const float* eWhh1 = (const float*)d_in[6];
    const float* eb1   = (const float*)d_in[7];
    const float* p1W   = (const float*)d_in[8];
    const float* p1b   = (const float*)d_in[9];
    const float* p2W   = (const float*)d_in[10];
    const float* p2b   = (const float*)d_in[11];
    const float* dWih  = (const float*)d_in[12];
    const float* dWhh  = (const float*)d_in[13];
    const float* db    = (const float*)d_in[14];
    const float* outW  = (const float*)d_in[15];
    const float* outb  = (const float*)d_in[16];

    float* ws    = (float*)d_ws;
    float* u0    = ws;                       // 2*L*64
    float* u1    = u0 + 2 * L * 64;          // 2*L*64
    float* out0p = u1 + 2 * L * 64;          // 2*L*64
    float* dec   = out0p + 2 * L * 64;       // L*26
    float* fin_h = dec + L * 2 * HID;        // 64
    float* fin_c = fin_h + 64;               // 64

    float* preds    = (float*)d_out;
    float* out_embs = preds + PRED_N;

    hipLaunchKernelGGL(k_emb_u0, dim3(L), dim3(160), 0, stream,
                       x, embW, eWih0, eb0, dWih, db, out_embs, u0, dec);

    hipLaunchKernelGGL(k_phase0, dim3(2 + GB), dim3(256), 0, stream,
                       u0, eWhh0, out0p, fin_h, fin_c,
                       dec, outW, outb, preds);

    hipLaunchKernelGGL(k_u1, dim3((L * 2 * 64 + 255) / 256), dim3(256), 0, stream,
                       out0p, eWih1, eb1, u1);

    hipLaunchKernelGGL(k_phase1, dim3(2), dim3(64), 0, stream,
                       u1, eWhh1, fin_h, fin_c);

    hipLaunchKernelGGL(k_tail, dim3((VOCAB + 255) / 256), dim3(256), 0, stream,
                       fin_h, fin_c, p1W, p1b, p2W, p2b, dWih, dWhh, db,
                       outW, outb, preds);
}